// Round 1
// baseline (277.075 us; speedup 1.0000x reference)
//
#include <hip/hip_runtime.h>

#define B_ 2
#define N_ 1024
#define C_ 256
#define P_ 256
#define K_ 27
#define M_ (P_ * K_)        // 6912
#define TOTKP (B_ * M_)     // 13824
#define NS 16
#define R2C 0.04f
#define QDIM 864            // 32*K_

// ---------------- ws layout (bytes) ----------------
// kp4    : float4[TOTKP]        @ 0        (221184)
// cnt    : int[TOTKP]           @ 221184   (55296)
// idx    : int[TOTKP*16]        @ 276480   (884736)
// F      : float[B_*N_*128]     @ 1161216  (1048576)
// pooled : float[TOTKP*32]      @ 2209792  (1769472)
// WrT    : float[QDIM*128]      @ 3979264  (442368)
// total ~4.42 MB

// ---------- kernel 1: F'[b,n,j] = b1[j] + sum_c sf[b,c,n]*W1[3+c,j] ----------
__global__ __launch_bounds__(128) void fpre_k(
    const float* __restrict__ sf, const float* __restrict__ W1,
    const float* __restrict__ b1, float* __restrict__ F)
{
    __shared__ __align__(16) float ssf[C_ * 8];
    int tid = threadIdx.x;
    int bid = blockIdx.x;          // 0..255
    int b = bid >> 7;
    int n0 = (bid & 127) * 8;
    for (int e = tid; e < C_ * 8; e += 128) {
        int c = e >> 3, i = e & 7;
        ssf[e] = sf[(b * C_ + c) * N_ + n0 + i];
    }
    __syncthreads();
    int j = tid;
    float acc[8];
    float bj = b1[j];
#pragma unroll
    for (int i = 0; i < 8; i++) acc[i] = bj;
#pragma unroll 4
    for (int c = 0; c < C_; ++c) {
        float w = W1[(3 + c) * 128 + j];
        const float4* sp = (const float4*)&ssf[c * 8];
        float4 sA = sp[0], sB = sp[1];
        acc[0] = fmaf(sA.x, w, acc[0]); acc[1] = fmaf(sA.y, w, acc[1]);
        acc[2] = fmaf(sA.z, w, acc[2]); acc[3] = fmaf(sA.w, w, acc[3]);
        acc[4] = fmaf(sB.x, w, acc[4]); acc[5] = fmaf(sB.y, w, acc[5]);
        acc[6] = fmaf(sB.z, w, acc[6]); acc[7] = fmaf(sB.w, w, acc[7]);
    }
#pragma unroll
    for (int i = 0; i < 8; i++) F[(b * N_ + n0 + i) * 128 + j] = acc[i];
}

// ---------- kernel 2: keypoints + ball query ----------
__global__ __launch_bounds__(256) void ballq_k(
    const float* __restrict__ seed_xyz, const float* __restrict__ boxes,
    const float* __restrict__ origins, const float* __restrict__ heading,
    float4* __restrict__ kp4, int* __restrict__ cntw, int* __restrict__ idxw)
{
    __shared__ __align__(16) float4 seeds[N_];
    int tid = threadIdx.x;
    int kpg = blockIdx.x * 256 + tid;     // 27 blocks per batch -> b uniform per block
    int b = kpg / M_;
    const float* sb = seed_xyz + b * (N_ * 3);
    for (int i = 0; i < 4; ++i) {
        int n = tid + i * 256;
        float x = sb[n * 3], y = sb[n * 3 + 1], z = sb[n * 3 + 2];
        float ss = __fadd_rn(__fadd_rn(__fmul_rn(x, x), __fmul_rn(y, y)), __fmul_rn(z, z));
        seeds[n] = make_float4(x, y, z, ss);
    }
    __syncthreads();

    int m = kpg - b * M_;
    int p = m / K_, a = m - p * K_;
    const float* bx = boxes + (b * P_ + p) * 6;
    const float* og = origins + (b * P_ + p) * 3;
    float th = heading[b * P_ + p];
    float di = (float)(a / 9), dj = (float)((a / 3) % 3), dk = (float)(a % 3);
    float s0 = __fadd_rn(bx[0], bx[3]);
    float s1 = __fadd_rn(bx[1], bx[4]);
    float s2 = __fadd_rn(bx[2], bx[5]);
    float lx = __fsub_rn(__fmul_rn(__fdiv_rn(__fadd_rn(di, 0.5f), 3.0f), s0), bx[0]);
    float ly = __fsub_rn(__fmul_rn(__fdiv_rn(__fadd_rn(dj, 0.5f), 3.0f), s1), bx[1]);
    float lz = __fsub_rn(__fmul_rn(__fdiv_rn(__fadd_rn(dk, 0.5f), 3.0f), s2), bx[2]);
    float ct = cosf(th), st = sinf(th);
    float kx = __fadd_rn(__fadd_rn(__fmul_rn(lx, ct), __fmul_rn(ly, st)), og[0]);
    float ky = __fadd_rn(__fadd_rn(__fmul_rn(lx, -st), __fmul_rn(ly, ct)), og[1]);
    float kz = __fadd_rn(lz, og[2]);
    kp4[kpg] = make_float4(kx, ky, kz, 0.f);
    float kk = __fadd_rn(__fadd_rn(__fmul_rn(kx, kx), __fmul_rn(ky, ky)), __fmul_rn(kz, kz));

    int cnt = 0;
    int* ip = idxw + kpg * NS;
    for (int n = 0; n < N_; ++n) {
        float4 sv = seeds[n];
        float dot = __fadd_rn(__fadd_rn(__fmul_rn(kx, sv.x), __fmul_rn(ky, sv.y)),
                              __fmul_rn(kz, sv.z));
        float d2 = __fsub_rn(__fadd_rn(kk, sv.w), __fmul_rn(2.0f, dot));
        if (d2 < R2C) {
            if (cnt < NS) ip[cnt] = n;
            cnt++;
        }
    }
    cntw[kpg] = cnt < NS ? cnt : NS;
}

// ---------- kernel 3: per-keypoint MLP + maxpool ----------
struct Ctx {
    const float* seed; const float* F;
    const float* sW2; const float* sW3;
    float* sH1; float* sH2;
    const int* ip;
    float4 kp;
    float w1x0, w1y0, w1z0, w1x1, w1y1, w1z1, b2j, b3t;
    int lane, t, jh, b, cnt, n0;
};

template <int GS>
static __device__ __forceinline__ void do_group(const Ctx& c, int s0, float& pool)
{
    float gx[GS], gy[GS], gz[GS];
    int nn[GS];
#pragma unroll
    for (int u = 0; u < GS; u++) {
        int s = s0 + u;
        int n = (s < c.cnt) ? c.ip[s] : c.n0;
        nn[u] = n;
        const float* sp = c.seed + (c.b * N_ + n) * 3;
        gx[u] = __fdiv_rn(__fsub_rn(sp[0], c.kp.x), 0.2f);
        gy[u] = __fdiv_rn(__fsub_rn(sp[1], c.kp.y), 0.2f);
        gz[u] = __fdiv_rn(__fsub_rn(sp[2], c.kp.z), 0.2f);
    }
#pragma unroll
    for (int u = 0; u < GS; u++) {
        const float* fp = c.F + (c.b * N_ + nn[u]) * 128;
        float v0 = fp[c.lane];
        float v1 = fp[c.lane + 64];
        v0 = fmaf(gx[u], c.w1x0, fmaf(gy[u], c.w1y0, fmaf(gz[u], c.w1z0, v0)));
        v1 = fmaf(gx[u], c.w1x1, fmaf(gy[u], c.w1y1, fmaf(gz[u], c.w1z1, v1)));
        c.sH1[u * 128 + c.lane] = fmaxf(v0, 0.f);
        c.sH1[u * 128 + c.lane + 64] = fmaxf(v1, 0.f);
    }
    // layer2: lane j = lane, all 64 outputs
    float acc[GS];
#pragma unroll
    for (int u = 0; u < GS; u++) acc[u] = c.b2j;
#pragma unroll
    for (int cc = 0; cc < 128; cc += 4) {
        float w0 = c.sW2[(cc + 0) * 64 + c.lane];
        float w1 = c.sW2[(cc + 1) * 64 + c.lane];
        float w2 = c.sW2[(cc + 2) * 64 + c.lane];
        float w3 = c.sW2[(cc + 3) * 64 + c.lane];
#pragma unroll
        for (int u = 0; u < GS; u++) {
            float4 h = *(const float4*)&c.sH1[u * 128 + cc];
            acc[u] = fmaf(h.x, w0, fmaf(h.y, w1, fmaf(h.z, w2, fmaf(h.w, w3, acc[u]))));
        }
    }
#pragma unroll
    for (int u = 0; u < GS; u++) c.sH2[u * 64 + c.lane] = fmaxf(acc[u], 0.f);
    // layer3: lane -> (t = lane&31 output, jh = lane>>5 half of the 64-reduction)
    float a3[GS];
#pragma unroll
    for (int u = 0; u < GS; u++) a3[u] = (c.jh == 0) ? c.b3t : 0.f;
#pragma unroll
    for (int jj = 0; jj < 32; jj += 4) {
        int j0 = c.jh * 32 + jj;
        float w0 = c.sW3[(j0 + 0) * 32 + c.t];
        float w1 = c.sW3[(j0 + 1) * 32 + c.t];
        float w2 = c.sW3[(j0 + 2) * 32 + c.t];
        float w3 = c.sW3[(j0 + 3) * 32 + c.t];
#pragma unroll
        for (int u = 0; u < GS; u++) {
            float4 h = *(const float4*)&c.sH2[u * 64 + j0];
            a3[u] = fmaf(h.x, w0, fmaf(h.y, w1, fmaf(h.z, w2, fmaf(h.w, w3, a3[u]))));
        }
    }
#pragma unroll
    for (int u = 0; u < GS; u++) {
        float v = a3[u] + __shfl_xor(a3[u], 32);
        pool = fmaxf(pool, fmaxf(v, 0.f));
    }
}

__global__ __launch_bounds__(256) void pool_k(
    const float* __restrict__ seed_xyz, const float* __restrict__ F,
    const float* __restrict__ W1, const float* __restrict__ b2g,
    const float* __restrict__ b3g, const float* __restrict__ W2g,
    const float* __restrict__ W3g, const float4* __restrict__ kp4,
    const int* __restrict__ cntw, const int* __restrict__ idxw,
    float* __restrict__ pooled)
{
    __shared__ __align__(16) float sW2[128 * 64];
    __shared__ __align__(16) float sW3[64 * 32];
    __shared__ __align__(16) float sH1[4 * 4 * 128];
    __shared__ __align__(16) float sH2[4 * 4 * 64];
    int tid = threadIdx.x;
    for (int e = tid; e < 2048; e += 256)
        ((float4*)sW2)[e] = ((const float4*)W2g)[e];
    for (int e = tid; e < 512; e += 256)
        ((float4*)sW3)[e] = ((const float4*)W3g)[e];
    __syncthreads();

    int wid = tid >> 6, lane = tid & 63;
    Ctx c;
    c.seed = seed_xyz; c.F = F;
    c.sW2 = sW2; c.sW3 = sW3;
    c.sH1 = sH1 + wid * 4 * 128;
    c.sH2 = sH2 + wid * 4 * 64;
    c.lane = lane; c.t = lane & 31; c.jh = lane >> 5;
    c.w1x0 = W1[lane];       c.w1x1 = W1[lane + 64];
    c.w1y0 = W1[128 + lane]; c.w1y1 = W1[128 + lane + 64];
    c.w1z0 = W1[256 + lane]; c.w1z1 = W1[256 + lane + 64];
    c.b2j = b2g[lane]; c.b3t = b3g[lane & 31];

    for (int i = 0; i < 4; ++i) {
        int kpg = blockIdx.x * 16 + wid * 4 + i;
        c.kp = kp4[kpg];
        c.cnt = cntw[kpg];
        c.ip = idxw + kpg * NS;
        c.b = kpg / M_;
        c.n0 = (c.cnt > 0) ? c.ip[0] : 0;
        int scnt = c.cnt < 1 ? 1 : c.cnt;
        float pool = 0.f;   // relu outputs >= 0, >=1 sample -> max >= 0
        for (int s0 = 0; s0 < scnt; s0 += 4) {
            int gs = scnt - s0; gs = gs > 4 ? 4 : gs;
            switch (gs) {
                case 1: do_group<1>(c, s0, pool); break;
                case 2: do_group<2>(c, s0, pool); break;
                case 3: do_group<3>(c, s0, pool); break;
                default: do_group<4>(c, s0, pool); break;
            }
        }
        if (lane < 32) pooled[kpg * 32 + lane] = pool;
    }
}

// ---------- kernel 4: WrT[q][j] = Wr[j][q] ----------
__global__ __launch_bounds__(256) void wrt_k(const float* __restrict__ Wr,
                                             float* __restrict__ WrT)
{
    int e = blockIdx.x * 256 + threadIdx.x;
    if (e < 128 * QDIM) {
        int j = e / QDIM, q = e - j * QDIM;
        WrT[q * 128 + j] = Wr[e];
    }
}

// ---------- kernel 5: out[b,j,p] = sum_q f[b,p,q]*WrT[q,j] + br[j] ----------
__global__ __launch_bounds__(256) void final_k(
    const float* __restrict__ pooled, const float* __restrict__ WrT,
    const float* __restrict__ br, float* __restrict__ out)
{
    __shared__ __align__(16) float ft[4 * QDIM];
    int tid = threadIdx.x;
    int blk = blockIdx.x;
    int b = blk >> 6;
    int pbase = (blk & 63) * 4;
    const float* src = pooled + (b * M_ + pbase * K_) * 32;
    for (int e = tid; e < 4 * K_ * 32; e += 256) {
        int rowk = e >> 5;              // p_i*27 + k
        int j32 = e & 31;
        int p_i = rowk / K_;
        int k = rowk - p_i * K_;
        ft[p_i * QDIM + j32 * K_ + k] = src[e];
    }
    __syncthreads();
    int j = tid & 127;
    int ph = tid >> 7;                  // p halves {ph, ph+2}
    float a0 = br[j], a1 = br[j];
    const float* f0 = ft + ph * QDIM;
    const float* f1 = ft + (ph + 2) * QDIM;
#pragma unroll 4
    for (int q = 0; q < QDIM; ++q) {
        float w = WrT[q * 128 + j];
        a0 = fmaf(f0[q], w, a0);
        a1 = fmaf(f1[q], w, a1);
    }
    out[(b * 128 + j) * P_ + pbase + ph] = a0;
    out[(b * 128 + j) * P_ + pbase + ph + 2] = a1;
}

extern "C" void kernel_launch(void* const* d_in, const int* in_sizes, int n_in,
                              void* d_out, int out_size, void* d_ws, size_t ws_size,
                              hipStream_t stream)
{
    const float* seed_xyz  = (const float*)d_in[0];
    const float* seed_feat = (const float*)d_in[1];
    const float* boxes     = (const float*)d_in[2];
    const float* origins   = (const float*)d_in[3];
    const float* heading   = (const float*)d_in[4];
    const float* W1        = (const float*)d_in[5];
    const float* b1        = (const float*)d_in[6];
    const float* W2        = (const float*)d_in[7];
    const float* b2        = (const float*)d_in[8];
    const float* W3        = (const float*)d_in[9];
    const float* b3        = (const float*)d_in[10];
    const float* Wr        = (const float*)d_in[11];
    const float* br        = (const float*)d_in[12];
    float* out = (float*)d_out;

    char* ws = (char*)d_ws;
    float4* kp4   = (float4*)(ws);
    int*    cntw  = (int*)(ws + 221184);
    int*    idxw  = (int*)(ws + 276480);
    float*  F     = (float*)(ws + 1161216);
    float*  pooled= (float*)(ws + 2209792);
    float*  WrT   = (float*)(ws + 3979264);

    fpre_k<<<dim3(256), dim3(128), 0, stream>>>(seed_feat, W1, b1, F);
    ballq_k<<<dim3(54), dim3(256), 0, stream>>>(seed_xyz, boxes, origins, heading,
                                                kp4, cntw, idxw);
    wrt_k<<<dim3(432), dim3(256), 0, stream>>>(Wr, WrT);
    pool_k<<<dim3(864), dim3(256), 0, stream>>>(seed_xyz, F, W1, b2, b3, W2, W3,
                                                kp4, cntw, idxw, pooled);
    final_k<<<dim3(128), dim3(256), 0, stream>>>(pooled, WrT, br, out);
}

// Round 2
// 209.962 us; speedup vs baseline: 1.3196x; 1.3196x over previous
//
#include <hip/hip_runtime.h>

#define B_ 2
#define N_ 1024
#define C_ 256
#define P_ 256
#define K_ 27
#define M_ (P_ * K_)        // 6912
#define TOTKP (B_ * M_)     // 13824
#define NS 16
#define R2C 0.04f
#define QDIM 864            // 32*K_

// ---------------- ws layout (bytes) ----------------
// kp4    : float4[TOTKP]        @ 0        (221184)
// cnt    : int[TOTKP]           @ 221184   (55296)
// idx    : int[TOTKP*16]        @ 276480   (884736)
// F      : float[B_*N_*128]     @ 1161216  (1048576)
// pooled : float[TOTKP*32]      @ 2209792  (1769472)
// WrT    : float[QDIM*128]      @ 3979264  (442368)

// ---------- kernel 1: F'[b,n,j] = b1[j] + sum_c sf[b,c,n]*W1[3+c,j] ----------
__global__ __launch_bounds__(128) void fpre_k(
    const float* __restrict__ sf, const float* __restrict__ W1,
    const float* __restrict__ b1, float* __restrict__ F)
{
    __shared__ __align__(16) float ssf[C_ * 8];
    int tid = threadIdx.x;
    int bid = blockIdx.x;          // 0..255
    int b = bid >> 7;
    int n0 = (bid & 127) * 8;
    for (int e = tid; e < C_ * 8; e += 128) {
        int c = e >> 3, i = e & 7;
        ssf[e] = sf[(b * C_ + c) * N_ + n0 + i];
    }
    __syncthreads();
    int j = tid;
    float acc[8];
    float bj = b1[j];
#pragma unroll
    for (int i = 0; i < 8; i++) acc[i] = bj;
#pragma unroll 4
    for (int c = 0; c < C_; ++c) {
        float w = W1[(3 + c) * 128 + j];
        const float4* sp = (const float4*)&ssf[c * 8];
        float4 sA = sp[0], sB = sp[1];
        acc[0] = fmaf(sA.x, w, acc[0]); acc[1] = fmaf(sA.y, w, acc[1]);
        acc[2] = fmaf(sA.z, w, acc[2]); acc[3] = fmaf(sA.w, w, acc[3]);
        acc[4] = fmaf(sB.x, w, acc[4]); acc[5] = fmaf(sB.y, w, acc[5]);
        acc[6] = fmaf(sB.z, w, acc[6]); acc[7] = fmaf(sB.w, w, acc[7]);
    }
#pragma unroll
    for (int i = 0; i < 8; i++) F[(b * N_ + n0 + i) * 128 + j] = acc[i];
}

// ---------- kernel 2: keypoints + ball query (wave-per-keypoint) ----------
__global__ __launch_bounds__(256) void ballq_k(
    const float* __restrict__ seed_xyz, const float* __restrict__ boxes,
    const float* __restrict__ origins, const float* __restrict__ heading,
    float4* __restrict__ kp4, int* __restrict__ cntw, int* __restrict__ idxw)
{
    int tid = threadIdx.x;
    int wid = tid >> 6, lane = tid & 63;
    int kpg = blockIdx.x * 4 + wid;       // one wave per keypoint
    int b = kpg / M_;
    int m = kpg - b * M_;
    int p = m / K_, a = m - p * K_;

    // keypoint (uniform across the wave; scalar-broadcast loads)
    const float* bx = boxes + (b * P_ + p) * 6;
    const float* og = origins + (b * P_ + p) * 3;
    float th = heading[b * P_ + p];
    float di = (float)(a / 9), dj = (float)((a / 3) % 3), dk = (float)(a % 3);
    float s0 = __fadd_rn(bx[0], bx[3]);
    float s1 = __fadd_rn(bx[1], bx[4]);
    float s2 = __fadd_rn(bx[2], bx[5]);
    float lx = __fsub_rn(__fmul_rn(__fdiv_rn(__fadd_rn(di, 0.5f), 3.0f), s0), bx[0]);
    float ly = __fsub_rn(__fmul_rn(__fdiv_rn(__fadd_rn(dj, 0.5f), 3.0f), s1), bx[1]);
    float lz = __fsub_rn(__fmul_rn(__fdiv_rn(__fadd_rn(dk, 0.5f), 3.0f), s2), bx[2]);
    float ct = cosf(th), st = sinf(th);
    float kx = __fadd_rn(__fadd_rn(__fmul_rn(lx, ct), __fmul_rn(ly, st)), og[0]);
    float ky = __fadd_rn(__fadd_rn(__fmul_rn(lx, -st), __fmul_rn(ly, ct)), og[1]);
    float kz = __fadd_rn(lz, og[2]);
    if (lane == 0) kp4[kpg] = make_float4(kx, ky, kz, 0.f);
    float kk = __fadd_rn(__fadd_rn(__fmul_rn(kx, kx), __fmul_rn(ky, ky)), __fmul_rn(kz, kz));

    // lane l tests seeds [16l, 16l+16): 192B contiguous, 12 x float4
    const float* sb = seed_xyz + b * (N_ * 3) + lane * 48;
    float f[48];
#pragma unroll
    for (int q = 0; q < 12; q++)
        ((float4*)f)[q] = ((const float4*)sb)[q];

    unsigned mask = 0;
#pragma unroll
    for (int i = 0; i < 16; i++) {
        float x = f[3 * i], y = f[3 * i + 1], z = f[3 * i + 2];
        float ss = __fadd_rn(__fadd_rn(__fmul_rn(x, x), __fmul_rn(y, y)), __fmul_rn(z, z));
        float dot = __fadd_rn(__fadd_rn(__fmul_rn(kx, x), __fmul_rn(ky, y)),
                              __fmul_rn(kz, z));
        float d2 = __fsub_rn(__fadd_rn(kk, ss), __fmul_rn(2.0f, dot));
        mask |= (d2 < R2C ? 1u : 0u) << i;
    }

    // wave-wide exclusive prefix sum of popcounts -> ordered compaction
    int pc = __popc(mask);
    int incl = pc;
#pragma unroll
    for (int d = 1; d < 64; d <<= 1) {
        int v = __shfl_up(incl, d);
        if (lane >= d) incl += v;
    }
    int total = __shfl(incl, 63);
    int base = incl - pc;

    int* ip = idxw + kpg * NS;
    unsigned mm = mask;
    while (mm && base < NS) {
        int i = __ffs(mm) - 1;
        mm &= mm - 1;
        ip[base++] = lane * 16 + i;
    }
    if (lane == 0) cntw[kpg] = total < NS ? total : NS;
}

// ---------- kernel 3: per-keypoint MLP + maxpool ----------
struct Ctx {
    const float* seed; const float* F;
    const float* sW2; const float* sW3;
    float* sH1; float* sH2;
    const int* ip;
    float4 kp;
    float w1x0, w1y0, w1z0, w1x1, w1y1, w1z1, b2j, b3t;
    int lane, t, jh, b, cnt, n0;
};

template <int GS>
static __device__ __forceinline__ void do_group(const Ctx& c, int s0, float& pool)
{
    float gx[GS], gy[GS], gz[GS];
    int nn[GS];
#pragma unroll
    for (int u = 0; u < GS; u++) {
        int s = s0 + u;
        int n = (s < c.cnt) ? c.ip[s] : c.n0;
        nn[u] = n;
        const float* sp = c.seed + (c.b * N_ + n) * 3;
        gx[u] = __fdiv_rn(__fsub_rn(sp[0], c.kp.x), 0.2f);
        gy[u] = __fdiv_rn(__fsub_rn(sp[1], c.kp.y), 0.2f);
        gz[u] = __fdiv_rn(__fsub_rn(sp[2], c.kp.z), 0.2f);
    }
#pragma unroll
    for (int u = 0; u < GS; u++) {
        const float* fp = c.F + (c.b * N_ + nn[u]) * 128;
        float v0 = fp[c.lane];
        float v1 = fp[c.lane + 64];
        v0 = fmaf(gx[u], c.w1x0, fmaf(gy[u], c.w1y0, fmaf(gz[u], c.w1z0, v0)));
        v1 = fmaf(gx[u], c.w1x1, fmaf(gy[u], c.w1y1, fmaf(gz[u], c.w1z1, v1)));
        c.sH1[u * 128 + c.lane] = fmaxf(v0, 0.f);
        c.sH1[u * 128 + c.lane + 64] = fmaxf(v1, 0.f);
    }
    // layer2: lane j = lane, all 64 outputs
    float acc[GS];
#pragma unroll
    for (int u = 0; u < GS; u++) acc[u] = c.b2j;
#pragma unroll
    for (int cc = 0; cc < 128; cc += 4) {
        float w0 = c.sW2[(cc + 0) * 64 + c.lane];
        float w1 = c.sW2[(cc + 1) * 64 + c.lane];
        float w2 = c.sW2[(cc + 2) * 64 + c.lane];
        float w3 = c.sW2[(cc + 3) * 64 + c.lane];
#pragma unroll
        for (int u = 0; u < GS; u++) {
            float4 h = *(const float4*)&c.sH1[u * 128 + cc];
            acc[u] = fmaf(h.x, w0, fmaf(h.y, w1, fmaf(h.z, w2, fmaf(h.w, w3, acc[u]))));
        }
    }
#pragma unroll
    for (int u = 0; u < GS; u++) c.sH2[u * 64 + c.lane] = fmaxf(acc[u], 0.f);
    // layer3: lane -> (t = lane&31 output, jh = lane>>5 half of the 64-reduction)
    float a3[GS];
#pragma unroll
    for (int u = 0; u < GS; u++) a3[u] = (c.jh == 0) ? c.b3t : 0.f;
#pragma unroll
    for (int jj = 0; jj < 32; jj += 4) {
        int j0 = c.jh * 32 + jj;
        float w0 = c.sW3[(j0 + 0) * 32 + c.t];
        float w1 = c.sW3[(j0 + 1) * 32 + c.t];
        float w2 = c.sW3[(j0 + 2) * 32 + c.t];
        float w3 = c.sW3[(j0 + 3) * 32 + c.t];
#pragma unroll
        for (int u = 0; u < GS; u++) {
            float4 h = *(const float4*)&c.sH2[u * 64 + j0];
            a3[u] = fmaf(h.x, w0, fmaf(h.y, w1, fmaf(h.z, w2, fmaf(h.w, w3, a3[u]))));
        }
    }
#pragma unroll
    for (int u = 0; u < GS; u++) {
        float v = a3[u] + __shfl_xor(a3[u], 32);
        pool = fmaxf(pool, fmaxf(v, 0.f));
    }
}

__global__ __launch_bounds__(256) void pool_k(
    const float* __restrict__ seed_xyz, const float* __restrict__ F,
    const float* __restrict__ W1, const float* __restrict__ b2g,
    const float* __restrict__ b3g, const float* __restrict__ W2g,
    const float* __restrict__ W3g, const float4* __restrict__ kp4,
    const int* __restrict__ cntw, const int* __restrict__ idxw,
    float* __restrict__ pooled)
{
    __shared__ __align__(16) float sW2[128 * 64];
    __shared__ __align__(16) float sW3[64 * 32];
    __shared__ __align__(16) float sH1[4 * 4 * 128];
    __shared__ __align__(16) float sH2[4 * 4 * 64];
    int tid = threadIdx.x;
    for (int e = tid; e < 2048; e += 256)
        ((float4*)sW2)[e] = ((const float4*)W2g)[e];
    for (int e = tid; e < 512; e += 256)
        ((float4*)sW3)[e] = ((const float4*)W3g)[e];
    __syncthreads();

    int wid = tid >> 6, lane = tid & 63;
    Ctx c;
    c.seed = seed_xyz; c.F = F;
    c.sW2 = sW2; c.sW3 = sW3;
    c.sH1 = sH1 + wid * 4 * 128;
    c.sH2 = sH2 + wid * 4 * 64;
    c.lane = lane; c.t = lane & 31; c.jh = lane >> 5;
    c.w1x0 = W1[lane];       c.w1x1 = W1[lane + 64];
    c.w1y0 = W1[128 + lane]; c.w1y1 = W1[128 + lane + 64];
    c.w1z0 = W1[256 + lane]; c.w1z1 = W1[256 + lane + 64];
    c.b2j = b2g[lane]; c.b3t = b3g[lane & 31];

    for (int i = 0; i < 4; ++i) {
        int kpg = blockIdx.x * 16 + wid * 4 + i;
        c.kp = kp4[kpg];
        c.cnt = cntw[kpg];
        c.ip = idxw + kpg * NS;
        c.b = kpg / M_;
        c.n0 = (c.cnt > 0) ? c.ip[0] : 0;
        int scnt = c.cnt < 1 ? 1 : c.cnt;
        float pool = 0.f;   // relu outputs >= 0, >=1 sample -> max >= 0
        for (int s0 = 0; s0 < scnt; s0 += 4) {
            int gs = scnt - s0; gs = gs > 4 ? 4 : gs;
            switch (gs) {
                case 1: do_group<1>(c, s0, pool); break;
                case 2: do_group<2>(c, s0, pool); break;
                case 3: do_group<3>(c, s0, pool); break;
                default: do_group<4>(c, s0, pool); break;
            }
        }
        if (lane < 32) pooled[kpg * 32 + lane] = pool;
    }
}

// ---------- kernel 4: WrT[q][j] = Wr[j][q] ----------
__global__ __launch_bounds__(256) void wrt_k(const float* __restrict__ Wr,
                                             float* __restrict__ WrT)
{
    int e = blockIdx.x * 256 + threadIdx.x;
    if (e < 128 * QDIM) {
        int j = e / QDIM, q = e - j * QDIM;
        WrT[q * 128 + j] = Wr[e];
    }
}

// ---------- kernel 5: out[b,j,p] = sum_q f[b,p,q]*WrT[q,j] + br[j] ----------
__global__ __launch_bounds__(256) void final_k(
    const float* __restrict__ pooled, const float* __restrict__ WrT,
    const float* __restrict__ br, float* __restrict__ out)
{
    __shared__ __align__(16) float ft[4 * QDIM];
    int tid = threadIdx.x;
    int blk = blockIdx.x;
    int b = blk >> 6;
    int pbase = (blk & 63) * 4;
    const float* src = pooled + (b * M_ + pbase * K_) * 32;
    for (int e = tid; e < 4 * K_ * 32; e += 256) {
        int rowk = e >> 5;              // p_i*27 + k
        int j32 = e & 31;
        int p_i = rowk / K_;
        int k = rowk - p_i * K_;
        ft[p_i * QDIM + j32 * K_ + k] = src[e];
    }
    __syncthreads();
    int j = tid & 127;
    int ph = tid >> 7;                  // p halves {ph, ph+2}
    float a0 = br[j], a1 = br[j];
    const float* f0 = ft + ph * QDIM;
    const float* f1 = ft + (ph + 2) * QDIM;
#pragma unroll 4
    for (int q = 0; q < QDIM; ++q) {
        float w = WrT[q * 128 + j];
        a0 = fmaf(f0[q], w, a0);
        a1 = fmaf(f1[q], w, a1);
    }
    out[(b * 128 + j) * P_ + pbase + ph] = a0;
    out[(b * 128 + j) * P_ + pbase + ph + 2] = a1;
}

extern "C" void kernel_launch(void* const* d_in, const int* in_sizes, int n_in,
                              void* d_out, int out_size, void* d_ws, size_t ws_size,
                              hipStream_t stream)
{
    const float* seed_xyz  = (const float*)d_in[0];
    const float* seed_feat = (const float*)d_in[1];
    const float* boxes     = (const float*)d_in[2];
    const float* origins   = (const float*)d_in[3];
    const float* heading   = (const float*)d_in[4];
    const float* W1        = (const float*)d_in[5];
    const float* b1        = (const float*)d_in[6];
    const float* W2        = (const float*)d_in[7];
    const float* b2        = (const float*)d_in[8];
    const float* W3        = (const float*)d_in[9];
    const float* b3        = (const float*)d_in[10];
    const float* Wr        = (const float*)d_in[11];
    const float* br        = (const float*)d_in[12];
    float* out = (float*)d_out;

    char* ws = (char*)d_ws;
    float4* kp4   = (float4*)(ws);
    int*    cntw  = (int*)(ws + 221184);
    int*    idxw  = (int*)(ws + 276480);
    float*  F     = (float*)(ws + 1161216);
    float*  pooled= (float*)(ws + 2209792);
    float*  WrT   = (float*)(ws + 3979264);

    fpre_k<<<dim3(256), dim3(128), 0, stream>>>(seed_feat, W1, b1, F);
    ballq_k<<<dim3(3456), dim3(256), 0, stream>>>(seed_xyz, boxes, origins, heading,
                                                  kp4, cntw, idxw);
    wrt_k<<<dim3(432), dim3(256), 0, stream>>>(Wr, WrT);
    pool_k<<<dim3(864), dim3(256), 0, stream>>>(seed_xyz, F, W1, b2, b3, W2, W3,
                                                kp4, cntw, idxw, pooled);
    final_k<<<dim3(128), dim3(256), 0, stream>>>(pooled, WrT, br, out);
}

// Round 3
// 167.388 us; speedup vs baseline: 1.6553x; 1.2543x over previous
//
#include <hip/hip_runtime.h>

#define B_ 2
#define N_ 1024
#define C_ 256
#define P_ 256
#define K_ 27
#define M_ (P_ * K_)        // 6912
#define TOTKP (B_ * M_)     // 13824
#define NS 16
#define R2C 0.04f
#define QDIM 864            // 32*K_

// ---------------- ws layout (bytes) ----------------
// kp4    : float4[TOTKP]        @ 0        (221184)
// cnt    : int[TOTKP]           @ 221184   (55296)
// idx    : int[TOTKP*16]        @ 276480   (884736)
// F      : float[B_*N_*128]     @ 1161216  (1048576)
// pooled : float[TOTKP*32]      @ 2209792  (1769472)
// WrT    : float[QDIM*128]      @ 3979264  (442368)
// partial: float[8*512*128]     @ 4421632  (2097152)   total ~6.52 MB

// ---------- kernel 1: F'[b,n,j] = b1[j] + sum_c sf[b,c,n]*W1[3+c,j] ----------
__global__ __launch_bounds__(128) void fpre_k(
    const float* __restrict__ sf, const float* __restrict__ W1,
    const float* __restrict__ b1, float* __restrict__ F)
{
    __shared__ __align__(16) float ssf[C_ * 8];
    int tid = threadIdx.x;
    int bid = blockIdx.x;          // 0..255
    int b = bid >> 7;
    int n0 = (bid & 127) * 8;
    for (int e = tid; e < C_ * 8; e += 128) {
        int c = e >> 3, i = e & 7;
        ssf[e] = sf[(b * C_ + c) * N_ + n0 + i];
    }
    __syncthreads();
    int j = tid;
    float acc[8];
    float bj = b1[j];
#pragma unroll
    for (int i = 0; i < 8; i++) acc[i] = bj;
#pragma unroll 4
    for (int c = 0; c < C_; ++c) {
        float w = W1[(3 + c) * 128 + j];
        const float4* sp = (const float4*)&ssf[c * 8];
        float4 sA = sp[0], sB = sp[1];
        acc[0] = fmaf(sA.x, w, acc[0]); acc[1] = fmaf(sA.y, w, acc[1]);
        acc[2] = fmaf(sA.z, w, acc[2]); acc[3] = fmaf(sA.w, w, acc[3]);
        acc[4] = fmaf(sB.x, w, acc[4]); acc[5] = fmaf(sB.y, w, acc[5]);
        acc[6] = fmaf(sB.z, w, acc[6]); acc[7] = fmaf(sB.w, w, acc[7]);
    }
#pragma unroll
    for (int i = 0; i < 8; i++) F[(b * N_ + n0 + i) * 128 + j] = acc[i];
}

// ---------- kernel 2: keypoints + ball query (wave-per-keypoint) ----------
__global__ __launch_bounds__(256) void ballq_k(
    const float* __restrict__ seed_xyz, const float* __restrict__ boxes,
    const float* __restrict__ origins, const float* __restrict__ heading,
    float4* __restrict__ kp4, int* __restrict__ cntw, int* __restrict__ idxw)
{
    int tid = threadIdx.x;
    int wid = tid >> 6, lane = tid & 63;
    int kpg = blockIdx.x * 4 + wid;       // one wave per keypoint
    int b = kpg / M_;
    int m = kpg - b * M_;
    int p = m / K_, a = m - p * K_;

    const float* bx = boxes + (b * P_ + p) * 6;
    const float* og = origins + (b * P_ + p) * 3;
    float th = heading[b * P_ + p];
    float di = (float)(a / 9), dj = (float)((a / 3) % 3), dk = (float)(a % 3);
    float s0 = __fadd_rn(bx[0], bx[3]);
    float s1 = __fadd_rn(bx[1], bx[4]);
    float s2 = __fadd_rn(bx[2], bx[5]);
    float lx = __fsub_rn(__fmul_rn(__fdiv_rn(__fadd_rn(di, 0.5f), 3.0f), s0), bx[0]);
    float ly = __fsub_rn(__fmul_rn(__fdiv_rn(__fadd_rn(dj, 0.5f), 3.0f), s1), bx[1]);
    float lz = __fsub_rn(__fmul_rn(__fdiv_rn(__fadd_rn(dk, 0.5f), 3.0f), s2), bx[2]);
    float ct = cosf(th), st = sinf(th);
    float kx = __fadd_rn(__fadd_rn(__fmul_rn(lx, ct), __fmul_rn(ly, st)), og[0]);
    float ky = __fadd_rn(__fadd_rn(__fmul_rn(lx, -st), __fmul_rn(ly, ct)), og[1]);
    float kz = __fadd_rn(lz, og[2]);
    if (lane == 0) kp4[kpg] = make_float4(kx, ky, kz, 0.f);
    float kk = __fadd_rn(__fadd_rn(__fmul_rn(kx, kx), __fmul_rn(ky, ky)), __fmul_rn(kz, kz));

    // lane l tests seeds [16l, 16l+16): 192B contiguous, 12 x float4
    const float* sb = seed_xyz + b * (N_ * 3) + lane * 48;
    float f[48];
#pragma unroll
    for (int q = 0; q < 12; q++)
        ((float4*)f)[q] = ((const float4*)sb)[q];

    unsigned mask = 0;
#pragma unroll
    for (int i = 0; i < 16; i++) {
        float x = f[3 * i], y = f[3 * i + 1], z = f[3 * i + 2];
        float ss = __fadd_rn(__fadd_rn(__fmul_rn(x, x), __fmul_rn(y, y)), __fmul_rn(z, z));
        float dot = __fadd_rn(__fadd_rn(__fmul_rn(kx, x), __fmul_rn(ky, y)),
                              __fmul_rn(kz, z));
        float d2 = __fsub_rn(__fadd_rn(kk, ss), __fmul_rn(2.0f, dot));
        mask |= (d2 < R2C ? 1u : 0u) << i;
    }

    int pc = __popc(mask);
    int incl = pc;
#pragma unroll
    for (int d = 1; d < 64; d <<= 1) {
        int v = __shfl_up(incl, d);
        if (lane >= d) incl += v;
    }
    int total = __shfl(incl, 63);
    int base = incl - pc;

    int* ip = idxw + kpg * NS;
    unsigned mm = mask;
    while (mm && base < NS) {
        int i = __ffs(mm) - 1;
        mm &= mm - 1;
        ip[base++] = lane * 16 + i;
    }
    if (lane == 0) cntw[kpg] = total < NS ? total : NS;
}

// ---------- kernel 3: per-keypoint MLP + maxpool ----------
struct Ctx {
    const float* seed; const float* F;
    const float* sW2; const float* sW3;
    float* sH1; float* sH2;
    const int* ip;
    float4 kp;
    float w1x0, w1y0, w1z0, w1x1, w1y1, w1z1, b2j, b3t;
    int lane, t, jh, b, cnt, n0;
};

template <int GS>
static __device__ __forceinline__ void do_group(const Ctx& c, int s0, float& pool)
{
    float gx[GS], gy[GS], gz[GS];
    int nn[GS];
#pragma unroll
    for (int u = 0; u < GS; u++) {
        int s = s0 + u;
        int n = (s < c.cnt) ? c.ip[s] : c.n0;
        nn[u] = n;
        const float* sp = c.seed + (c.b * N_ + n) * 3;
        gx[u] = __fdiv_rn(__fsub_rn(sp[0], c.kp.x), 0.2f);
        gy[u] = __fdiv_rn(__fsub_rn(sp[1], c.kp.y), 0.2f);
        gz[u] = __fdiv_rn(__fsub_rn(sp[2], c.kp.z), 0.2f);
    }
#pragma unroll
    for (int u = 0; u < GS; u++) {
        const float* fp = c.F + (c.b * N_ + nn[u]) * 128;
        float v0 = fp[c.lane];
        float v1 = fp[c.lane + 64];
        v0 = fmaf(gx[u], c.w1x0, fmaf(gy[u], c.w1y0, fmaf(gz[u], c.w1z0, v0)));
        v1 = fmaf(gx[u], c.w1x1, fmaf(gy[u], c.w1y1, fmaf(gz[u], c.w1z1, v1)));
        c.sH1[u * 128 + c.lane] = fmaxf(v0, 0.f);
        c.sH1[u * 128 + c.lane + 64] = fmaxf(v1, 0.f);
    }
    float acc[GS];
#pragma unroll
    for (int u = 0; u < GS; u++) acc[u] = c.b2j;
#pragma unroll
    for (int cc = 0; cc < 128; cc += 4) {
        float w0 = c.sW2[(cc + 0) * 64 + c.lane];
        float w1 = c.sW2[(cc + 1) * 64 + c.lane];
        float w2 = c.sW2[(cc + 2) * 64 + c.lane];
        float w3 = c.sW2[(cc + 3) * 64 + c.lane];
#pragma unroll
        for (int u = 0; u < GS; u++) {
            float4 h = *(const float4*)&c.sH1[u * 128 + cc];
            acc[u] = fmaf(h.x, w0, fmaf(h.y, w1, fmaf(h.z, w2, fmaf(h.w, w3, acc[u]))));
        }
    }
#pragma unroll
    for (int u = 0; u < GS; u++) c.sH2[u * 64 + c.lane] = fmaxf(acc[u], 0.f);
    float a3[GS];
#pragma unroll
    for (int u = 0; u < GS; u++) a3[u] = (c.jh == 0) ? c.b3t : 0.f;
#pragma unroll
    for (int jj = 0; jj < 32; jj += 4) {
        int j0 = c.jh * 32 + jj;
        float w0 = c.sW3[(j0 + 0) * 32 + c.t];
        float w1 = c.sW3[(j0 + 1) * 32 + c.t];
        float w2 = c.sW3[(j0 + 2) * 32 + c.t];
        float w3 = c.sW3[(j0 + 3) * 32 + c.t];
#pragma unroll
        for (int u = 0; u < GS; u++) {
            float4 h = *(const float4*)&c.sH2[u * 64 + j0];
            a3[u] = fmaf(h.x, w0, fmaf(h.y, w1, fmaf(h.z, w2, fmaf(h.w, w3, a3[u]))));
        }
    }
#pragma unroll
    for (int u = 0; u < GS; u++) {
        float v = a3[u] + __shfl_xor(a3[u], 32);
        pool = fmaxf(pool, fmaxf(v, 0.f));
    }
}

__global__ __launch_bounds__(256) void pool_k(
    const float* __restrict__ seed_xyz, const float* __restrict__ F,
    const float* __restrict__ W1, const float* __restrict__ b2g,
    const float* __restrict__ b3g, const float* __restrict__ W2g,
    const float* __restrict__ W3g, const float4* __restrict__ kp4,
    const int* __restrict__ cntw, const int* __restrict__ idxw,
    float* __restrict__ pooled)
{
    __shared__ __align__(16) float sW2[128 * 64];
    __shared__ __align__(16) float sW3[64 * 32];
    __shared__ __align__(16) float sH1[4 * 4 * 128];
    __shared__ __align__(16) float sH2[4 * 4 * 64];
    int tid = threadIdx.x;
    for (int e = tid; e < 2048; e += 256)
        ((float4*)sW2)[e] = ((const float4*)W2g)[e];
    for (int e = tid; e < 512; e += 256)
        ((float4*)sW3)[e] = ((const float4*)W3g)[e];
    __syncthreads();

    int wid = tid >> 6, lane = tid & 63;
    Ctx c;
    c.seed = seed_xyz; c.F = F;
    c.sW2 = sW2; c.sW3 = sW3;
    c.sH1 = sH1 + wid * 4 * 128;
    c.sH2 = sH2 + wid * 4 * 64;
    c.lane = lane; c.t = lane & 31; c.jh = lane >> 5;
    c.w1x0 = W1[lane];       c.w1x1 = W1[lane + 64];
    c.w1y0 = W1[128 + lane]; c.w1y1 = W1[128 + lane + 64];
    c.w1z0 = W1[256 + lane]; c.w1z1 = W1[256 + lane + 64];
    c.b2j = b2g[lane]; c.b3t = b3g[lane & 31];

    for (int i = 0; i < 4; ++i) {
        int kpg = blockIdx.x * 16 + wid * 4 + i;
        c.kp = kp4[kpg];
        c.cnt = cntw[kpg];
        c.ip = idxw + kpg * NS;
        c.b = kpg / M_;
        c.n0 = (c.cnt > 0) ? c.ip[0] : 0;
        int scnt = c.cnt < 1 ? 1 : c.cnt;
        float pool = 0.f;
        for (int s0 = 0; s0 < scnt; s0 += 4) {
            int gs = scnt - s0; gs = gs > 4 ? 4 : gs;
            switch (gs) {
                case 1: do_group<1>(c, s0, pool); break;
                case 2: do_group<2>(c, s0, pool); break;
                case 3: do_group<3>(c, s0, pool); break;
                default: do_group<4>(c, s0, pool); break;
            }
        }
        if (lane < 32) pooled[kpg * 32 + lane] = pool;
    }
}

// ---------- kernel 4: WrT[q][j] = Wr[j][q] ----------
__global__ __launch_bounds__(256) void wrt_k(const float* __restrict__ Wr,
                                             float* __restrict__ WrT)
{
    int e = blockIdx.x * 256 + threadIdx.x;
    if (e < 128 * QDIM) {
        int j = e / QDIM, q = e - j * QDIM;
        WrT[q * 128 + j] = Wr[e];
    }
}

// ---------- kernel 5: split-K GEMM. chunk c covers j32 in [4c,4c+4)  ----------
// q_global = j32*27 + k = 108c + (jo*27 + k); source elem = rowbase + k*32 + 4c + jo
__global__ __launch_bounds__(256) void final_k(
    const float* __restrict__ pooled, const float* __restrict__ WrT,
    float* __restrict__ partial)
{
    __shared__ __align__(16) float ft[8][108];
    int tid = threadIdx.x;
    int blk = blockIdx.x;
    int c = blk & 7;          // K-chunk
    int mt = blk >> 3;        // 0..63, rows mt*8 .. mt*8+7
    if (tid < 216) {
        int ri = tid / 27, k = tid - ri * 27;
        int row = mt * 8 + ri;
        int b = row >> 8, p = row & 255;
        const float* sp = pooled + ((b * M_ + p * K_) + k) * 32 + c * 4;
        float4 v = *(const float4*)sp;
        float* fp = &ft[ri][0];
        fp[k] = v.x; fp[27 + k] = v.y; fp[54 + k] = v.z; fp[81 + k] = v.w;
    }
    __syncthreads();
    int j = tid & 127;
    int rh = tid >> 7;        // rows rh*4 .. rh*4+3
    float a0 = 0.f, a1 = 0.f, a2 = 0.f, a3 = 0.f;
    const float* wp = WrT + (c * 108) * 128 + j;
    const float* f0 = &ft[rh * 4 + 0][0];
    const float* f1 = &ft[rh * 4 + 1][0];
    const float* f2 = &ft[rh * 4 + 2][0];
    const float* f3 = &ft[rh * 4 + 3][0];
#pragma unroll 4
    for (int q = 0; q < 108; ++q) {
        float w = wp[q * 128];
        a0 = fmaf(f0[q], w, a0);
        a1 = fmaf(f1[q], w, a1);
        a2 = fmaf(f2[q], w, a2);
        a3 = fmaf(f3[q], w, a3);
    }
    int row0 = mt * 8 + rh * 4;
    partial[(c * 512 + row0 + 0) * 128 + j] = a0;
    partial[(c * 512 + row0 + 1) * 128 + j] = a1;
    partial[(c * 512 + row0 + 2) * 128 + j] = a2;
    partial[(c * 512 + row0 + 3) * 128 + j] = a3;
}

// ---------- kernel 6: out[b,j,p] = br[j] + sum_c partial[c][row][j] ----------
__global__ __launch_bounds__(256) void fred_k(
    const float* __restrict__ partial, const float* __restrict__ br,
    float* __restrict__ out)
{
    int id = blockIdx.x * 256 + threadIdx.x;   // 65536
    int j = id & 127;
    int row = id >> 7;                          // 0..511
    int b = row >> 8, p = row & 255;
    float s = br[j];
#pragma unroll
    for (int c = 0; c < 8; ++c)
        s += partial[(c * 512 + row) * 128 + j];
    out[(b * 128 + j) * 256 + p] = s;
}

extern "C" void kernel_launch(void* const* d_in, const int* in_sizes, int n_in,
                              void* d_out, int out_size, void* d_ws, size_t ws_size,
                              hipStream_t stream)
{
    const float* seed_xyz  = (const float*)d_in[0];
    const float* seed_feat = (const float*)d_in[1];
    const float* boxes     = (const float*)d_in[2];
    const float* origins   = (const float*)d_in[3];
    const float* heading   = (const float*)d_in[4];
    const float* W1        = (const float*)d_in[5];
    const float* b1        = (const float*)d_in[6];
    const float* W2        = (const float*)d_in[7];
    const float* b2        = (const float*)d_in[8];
    const float* W3        = (const float*)d_in[9];
    const float* b3        = (const float*)d_in[10];
    const float* Wr        = (const float*)d_in[11];
    const float* br        = (const float*)d_in[12];
    float* out = (float*)d_out;

    char* ws = (char*)d_ws;
    float4* kp4    = (float4*)(ws);
    int*    cntw   = (int*)(ws + 221184);
    int*    idxw   = (int*)(ws + 276480);
    float*  F      = (float*)(ws + 1161216);
    float*  pooled = (float*)(ws + 2209792);
    float*  WrT    = (float*)(ws + 3979264);
    float*  part   = (float*)(ws + 4421632);

    fpre_k<<<dim3(256), dim3(128), 0, stream>>>(seed_feat, W1, b1, F);
    ballq_k<<<dim3(3456), dim3(256), 0, stream>>>(seed_xyz, boxes, origins, heading,
                                                  kp4, cntw, idxw);
    wrt_k<<<dim3(432), dim3(256), 0, stream>>>(Wr, WrT);
    pool_k<<<dim3(864), dim3(256), 0, stream>>>(seed_xyz, F, W1, b2, b3, W2, W3,
                                                kp4, cntw, idxw, pooled);
    final_k<<<dim3(512), dim3(256), 0, stream>>>(pooled, WrT, part);
    fred_k<<<dim3(256), dim3(256), 0, stream>>>(part, br, out);
}

// Round 8
// 161.974 us; speedup vs baseline: 1.7106x; 1.0334x over previous
//
#include <hip/hip_runtime.h>

#define B_ 2
#define N_ 1024
#define C_ 256
#define P_ 256
#define K_ 27
#define M_ (P_ * K_)        // 6912
#define TOTKP (B_ * M_)     // 13824
#define NS 16
#define R2C 0.04f
#define QDIM 864            // 32*K_

// ---------------- ws layout (bytes) ----------------
// kp4    : float4[TOTKP]        @ 0        (221184)
// cnt    : int[TOTKP]           @ 221184   (55296)
// idx    : int[TOTKP*16]        @ 276480   (884736)
// F      : float[B_*N_*128]     @ 1161216  (1048576)
// pooled : float[TOTKP*32]      @ 2209792  (1769472)
// WrT    : float[QDIM*128]      @ 3979264  (442368)  total ~4.42 MB

// prep_k blockIdx ranges
#define PREP_FPRE0   0
#define PREP_WRT0    256      // 108 blocks
#define PREP_OINIT0  364      // 256 blocks
#define PREP_BALLQ0  620      // 3456 blocks
#define PREP_NBLK    4076

// ---------- fused prep: fpre + WrT transpose + out=br + ball query ----------
__global__ __launch_bounds__(256) void prep_k(
    const float* __restrict__ sf, const float* __restrict__ W1,
    const float* __restrict__ b1, const float* __restrict__ Wr,
    const float* __restrict__ br, const float* __restrict__ seed_xyz,
    const float* __restrict__ boxes, const float* __restrict__ origins,
    const float* __restrict__ heading,
    float* __restrict__ F, float* __restrict__ WrT, float* __restrict__ out,
    float4* __restrict__ kp4, int* __restrict__ cntw, int* __restrict__ idxw)
{
    __shared__ __align__(16) float ssf[C_ * 8];
    int tid = threadIdx.x;
    int bid = blockIdx.x;

    if (bid < PREP_WRT0) {
        // ---- task A: F'[b,n,j] = b1[j] + sum_c sf[b,c,n]*W1[3+c,j] ----
        int b = bid >> 7;
        int n0 = (bid & 127) * 8;
        for (int e = tid; e < C_ * 8; e += 256) {
            int c = e >> 3, i = e & 7;
            ssf[e] = sf[(b * C_ + c) * N_ + n0 + i];
        }
        __syncthreads();
        int j = tid & 127;
        int h = tid >> 7;               // 4-seed half
        float acc[4];
        float bj = b1[j];
#pragma unroll
        for (int i = 0; i < 4; i++) acc[i] = bj;
#pragma unroll 8
        for (int c = 0; c < C_; ++c) {
            float w = W1[(3 + c) * 128 + j];
            float4 s = *(const float4*)&ssf[c * 8 + h * 4];
            acc[0] = fmaf(s.x, w, acc[0]);
            acc[1] = fmaf(s.y, w, acc[1]);
            acc[2] = fmaf(s.z, w, acc[2]);
            acc[3] = fmaf(s.w, w, acc[3]);
        }
#pragma unroll
        for (int i = 0; i < 4; i++)
            F[(b * N_ + n0 + h * 4 + i) * 128 + j] = acc[i];
    } else if (bid < PREP_OINIT0) {
        // ---- task B: WrT[q][j] = Wr[j][q], float4 reads ----
        int e4 = (bid - PREP_WRT0) * 256 + tid;       // < 27648
        int j = e4 / 216, qq = e4 - j * 216;
        float4 v = ((const float4*)(Wr + j * QDIM))[qq];
        int q0 = qq * 4;
        WrT[(q0 + 0) * 128 + j] = v.x;
        WrT[(q0 + 1) * 128 + j] = v.y;
        WrT[(q0 + 2) * 128 + j] = v.z;
        WrT[(q0 + 3) * 128 + j] = v.w;
    } else if (bid < PREP_BALLQ0) {
        // ---- task C: out[id] = br[(id>>8)&127] ----
        int id = (bid - PREP_OINIT0) * 256 + tid;     // < 65536
        out[id] = br[(id >> 8) & 127];
    } else {
        // ---- task D: keypoints + ball query (wave per keypoint) ----
        int wid = tid >> 6, lane = tid & 63;
        int kpg = (bid - PREP_BALLQ0) * 4 + wid;
        int b = kpg / M_;
        int m = kpg - b * M_;
        int p = m / K_, a = m - p * K_;

        const float* bx = boxes + (b * P_ + p) * 6;
        const float* og = origins + (b * P_ + p) * 3;
        float th = heading[b * P_ + p];
        float di = (float)(a / 9), dj = (float)((a / 3) % 3), dk = (float)(a % 3);
        float s0 = __fadd_rn(bx[0], bx[3]);
        float s1 = __fadd_rn(bx[1], bx[4]);
        float s2 = __fadd_rn(bx[2], bx[5]);
        float lx = __fsub_rn(__fmul_rn(__fdiv_rn(__fadd_rn(di, 0.5f), 3.0f), s0), bx[0]);
        float ly = __fsub_rn(__fmul_rn(__fdiv_rn(__fadd_rn(dj, 0.5f), 3.0f), s1), bx[1]);
        float lz = __fsub_rn(__fmul_rn(__fdiv_rn(__fadd_rn(dk, 0.5f), 3.0f), s2), bx[2]);
        float ct = cosf(th), st = sinf(th);
        float kx = __fadd_rn(__fadd_rn(__fmul_rn(lx, ct), __fmul_rn(ly, st)), og[0]);
        float ky = __fadd_rn(__fadd_rn(__fmul_rn(lx, -st), __fmul_rn(ly, ct)), og[1]);
        float kz = __fadd_rn(lz, og[2]);
        if (lane == 0) kp4[kpg] = make_float4(kx, ky, kz, 0.f);
        float kk = __fadd_rn(__fadd_rn(__fmul_rn(kx, kx), __fmul_rn(ky, ky)),
                             __fmul_rn(kz, kz));

        const float* sb = seed_xyz + b * (N_ * 3) + lane * 48;
        float f[48];
#pragma unroll
        for (int q = 0; q < 12; q++)
            ((float4*)f)[q] = ((const float4*)sb)[q];

        unsigned mask = 0;
#pragma unroll
        for (int i = 0; i < 16; i++) {
            float x = f[3 * i], y = f[3 * i + 1], z = f[3 * i + 2];
            float ss = __fadd_rn(__fadd_rn(__fmul_rn(x, x), __fmul_rn(y, y)),
                                 __fmul_rn(z, z));
            float dot = __fadd_rn(__fadd_rn(__fmul_rn(kx, x), __fmul_rn(ky, y)),
                                  __fmul_rn(kz, z));
            float d2 = __fsub_rn(__fadd_rn(kk, ss), __fmul_rn(2.0f, dot));
            mask |= (d2 < R2C ? 1u : 0u) << i;
        }

        int pc = __popc(mask);
        int incl = pc;
#pragma unroll
        for (int d = 1; d < 64; d <<= 1) {
            int v = __shfl_up(incl, d);
            if (lane >= d) incl += v;
        }
        int total = __shfl(incl, 63);
        int base = incl - pc;

        int* ip = idxw + kpg * NS;
        unsigned mm = mask;
        while (mm && base < NS) {
            int i = __ffs(mm) - 1;
            mm &= mm - 1;
            ip[base++] = lane * 16 + i;
        }
        if (lane == 0) cntw[kpg] = total < NS ? total : NS;
    }
}

// ---------- kernel 2: per-keypoint MLP + maxpool ----------
struct Ctx {
    const float* seed; const float* F;
    const float* sW2; const float* sW3;
    float* sH1; float* sH2;
    const int* ip;
    float4 kp;
    float w1x0, w1y0, w1z0, w1x1, w1y1, w1z1, b2j, b3t;
    int lane, t, jh, b, cnt, n0;
};

template <int GS>
static __device__ __forceinline__ void do_group(const Ctx& c, int s0, float& pool)
{
    float gx[GS], gy[GS], gz[GS];
    int nn[GS];
#pragma unroll
    for (int u = 0; u < GS; u++) {
        int s = s0 + u;
        int n = (s < c.cnt) ? c.ip[s] : c.n0;
        nn[u] = n;
        const float* sp = c.seed + (c.b * N_ + n) * 3;
        gx[u] = __fdiv_rn(__fsub_rn(sp[0], c.kp.x), 0.2f);
        gy[u] = __fdiv_rn(__fsub_rn(sp[1], c.kp.y), 0.2f);
        gz[u] = __fdiv_rn(__fsub_rn(sp[2], c.kp.z), 0.2f);
    }
#pragma unroll
    for (int u = 0; u < GS; u++) {
        const float* fp = c.F + (c.b * N_ + nn[u]) * 128;
        float v0 = fp[c.lane];
        float v1 = fp[c.lane + 64];
        v0 = fmaf(gx[u], c.w1x0, fmaf(gy[u], c.w1y0, fmaf(gz[u], c.w1z0, v0)));
        v1 = fmaf(gx[u], c.w1x1, fmaf(gy[u], c.w1y1, fmaf(gz[u], c.w1z1, v1)));
        c.sH1[u * 128 + c.lane] = fmaxf(v0, 0.f);
        c.sH1[u * 128 + c.lane + 64] = fmaxf(v1, 0.f);
    }
    float acc[GS];
#pragma unroll
    for (int u = 0; u < GS; u++) acc[u] = c.b2j;
#pragma unroll
    for (int cc = 0; cc < 128; cc += 4) {
        float w0 = c.sW2[(cc + 0) * 64 + c.lane];
        float w1 = c.sW2[(cc + 1) * 64 + c.lane];
        float w2 = c.sW2[(cc + 2) * 64 + c.lane];
        float w3 = c.sW2[(cc + 3) * 64 + c.lane];
#pragma unroll
        for (int u = 0; u < GS; u++) {
            float4 h = *(const float4*)&c.sH1[u * 128 + cc];
            acc[u] = fmaf(h.x, w0, fmaf(h.y, w1, fmaf(h.z, w2, fmaf(h.w, w3, acc[u]))));
        }
    }
#pragma unroll
    for (int u = 0; u < GS; u++) c.sH2[u * 64 + c.lane] = fmaxf(acc[u], 0.f);
    float a3[GS];
#pragma unroll
    for (int u = 0; u < GS; u++) a3[u] = (c.jh == 0) ? c.b3t : 0.f;
#pragma unroll
    for (int jj = 0; jj < 32; jj += 4) {
        int j0 = c.jh * 32 + jj;
        float w0 = c.sW3[(j0 + 0) * 32 + c.t];
        float w1 = c.sW3[(j0 + 1) * 32 + c.t];
        float w2 = c.sW3[(j0 + 2) * 32 + c.t];
        float w3 = c.sW3[(j0 + 3) * 32 + c.t];
#pragma unroll
        for (int u = 0; u < GS; u++) {
            float4 h = *(const float4*)&c.sH2[u * 64 + j0];
            a3[u] = fmaf(h.x, w0, fmaf(h.y, w1, fmaf(h.z, w2, fmaf(h.w, w3, a3[u]))));
        }
    }
#pragma unroll
    for (int u = 0; u < GS; u++) {
        float v = a3[u] + __shfl_xor(a3[u], 32);
        pool = fmaxf(pool, fmaxf(v, 0.f));
    }
}

__global__ __launch_bounds__(256) void pool_k(
    const float* __restrict__ seed_xyz, const float* __restrict__ F,
    const float* __restrict__ W1, const float* __restrict__ b2g,
    const float* __restrict__ b3g, const float* __restrict__ W2g,
    const float* __restrict__ W3g, const float4* __restrict__ kp4,
    const int* __restrict__ cntw, const int* __restrict__ idxw,
    float* __restrict__ pooled)
{
    __shared__ __align__(16) float sW2[128 * 64];
    __shared__ __align__(16) float sW3[64 * 32];
    __shared__ __align__(16) float sH1[4 * 4 * 128];
    __shared__ __align__(16) float sH2[4 * 4 * 64];
    int tid = threadIdx.x;
    for (int e = tid; e < 2048; e += 256)
        ((float4*)sW2)[e] = ((const float4*)W2g)[e];
    for (int e = tid; e < 512; e += 256)
        ((float4*)sW3)[e] = ((const float4*)W3g)[e];
    __syncthreads();

    int wid = tid >> 6, lane = tid & 63;
    Ctx c;
    c.seed = seed_xyz; c.F = F;
    c.sW2 = sW2; c.sW3 = sW3;
    c.sH1 = sH1 + wid * 4 * 128;
    c.sH2 = sH2 + wid * 4 * 64;
    c.lane = lane; c.t = lane & 31; c.jh = lane >> 5;
    c.w1x0 = W1[lane];       c.w1x1 = W1[lane + 64];
    c.w1y0 = W1[128 + lane]; c.w1y1 = W1[128 + lane + 64];
    c.w1z0 = W1[256 + lane]; c.w1z1 = W1[256 + lane + 64];
    c.b2j = b2g[lane]; c.b3t = b3g[lane & 31];

    for (int i = 0; i < 2; ++i) {
        int kpg = blockIdx.x * 8 + wid * 2 + i;
        c.kp = kp4[kpg];
        c.cnt = cntw[kpg];
        c.ip = idxw + kpg * NS;
        c.b = kpg / M_;
        c.n0 = (c.cnt > 0) ? c.ip[0] : 0;
        int scnt = c.cnt < 1 ? 1 : c.cnt;
        float pool = 0.f;
        for (int s0 = 0; s0 < scnt; s0 += 4) {
            int gs = scnt - s0; gs = gs > 4 ? 4 : gs;
            switch (gs) {
                case 1: do_group<1>(c, s0, pool); break;
                case 2: do_group<2>(c, s0, pool); break;
                case 3: do_group<3>(c, s0, pool); break;
                default: do_group<4>(c, s0, pool); break;
            }
        }
        if (lane < 32) pooled[kpg * 32 + lane] = pool;
    }
}

// ---------- kernel 3: split-K GEMM, atomic accumulate into out ----------
// chunk c covers j32 in [4c,4c+4); q_global = 108c + (jo*27 + k)
__global__ __launch_bounds__(256) void final_k(
    const float* __restrict__ pooled, const float* __restrict__ WrT,
    float* __restrict__ out)
{
    __shared__ __align__(16) float ft[8][108];
    int tid = threadIdx.x;
    int blk = blockIdx.x;
    int c = blk & 7;          // K-chunk
    int mt = blk >> 3;        // 0..63, rows mt*8 .. mt*8+7
    if (tid < 216) {
        int ri = tid / 27, k = tid - ri * 27;
        int row = mt * 8 + ri;
        int b = row >> 8, p = row & 255;
        const float* sp = pooled + ((b * M_ + p * K_) + k) * 32 + c * 4;
        float4 v = *(const float4*)sp;
        float* fp = &ft[ri][0];
        fp[k] = v.x; fp[27 + k] = v.y; fp[54 + k] = v.z; fp[81 + k] = v.w;
    }
    __syncthreads();
    int j = tid & 127;
    int rh = tid >> 7;        // rows rh*4 .. rh*4+3
    float a0 = 0.f, a1 = 0.f, a2 = 0.f, a3 = 0.f;
    const float* wp = WrT + (c * 108) * 128 + j;
    const float* f0 = &ft[rh * 4 + 0][0];
    const float* f1 = &ft[rh * 4 + 1][0];
    const float* f2 = &ft[rh * 4 + 2][0];
    const float* f3 = &ft[rh * 4 + 3][0];
#pragma unroll 4
    for (int q = 0; q < 108; ++q) {
        float w = wp[q * 128];
        a0 = fmaf(f0[q], w, a0);
        a1 = fmaf(f1[q], w, a1);
        a2 = fmaf(f2[q], w, a2);
        a3 = fmaf(f3[q], w, a3);
    }
    int row0 = mt * 8 + rh * 4;
    int b0 = row0 >> 8;
    int p0 = row0 & 255;
    float* op = out + b0 * 128 * 256 + j * 256 + p0;
    atomicAdd(op + 0, a0);
    atomicAdd(op + 1, a1);
    atomicAdd(op + 2, a2);
    atomicAdd(op + 3, a3);
}

extern "C" void kernel_launch(void* const* d_in, const int* in_sizes, int n_in,
                              void* d_out, int out_size, void* d_ws, size_t ws_size,
                              hipStream_t stream)
{
    const float* seed_xyz  = (const float*)d_in[0];
    const float* seed_feat = (const float*)d_in[1];
    const float* boxes     = (const float*)d_in[2];
    const float* origins   = (const float*)d_in[3];
    const float* heading   = (const float*)d_in[4];
    const float* W1        = (const float*)d_in[5];
    const float* b1        = (const float*)d_in[6];
    const float* W2        = (const float*)d_in[7];
    const float* b2        = (const float*)d_in[8];
    const float* W3        = (const float*)d_in[9];
    const float* b3        = (const float*)d_in[10];
    const float* Wr        = (const float*)d_in[11];
    const float* br        = (const float*)d_in[12];
    float* out = (float*)d_out;

    char* ws = (char*)d_ws;
    float4* kp4    = (float4*)(ws);
    int*    cntw   = (int*)(ws + 221184);
    int*    idxw   = (int*)(ws + 276480);
    float*  F      = (float*)(ws + 1161216);
    float*  pooled = (float*)(ws + 2209792);
    float*  WrT    = (float*)(ws + 3979264);

    prep_k<<<dim3(PREP_NBLK), dim3(256), 0, stream>>>(
        seed_feat, W1, b1, Wr, br, seed_xyz, boxes, origins, heading,
        F, WrT, out, kp4, cntw, idxw);
    pool_k<<<dim3(1728), dim3(256), 0, stream>>>(seed_xyz, F, W1, b2, b3, W2, W3,
                                                 kp4, cntw, idxw, pooled);
    final_k<<<dim3(512), dim3(256), 0, stream>>>(pooled, WrT, out);
}

// Round 11
// 148.481 us; speedup vs baseline: 1.8661x; 1.0909x over previous
//
#include <hip/hip_runtime.h>

#define B_ 2
#define N_ 1024
#define C_ 256
#define P_ 256
#define K_ 27
#define M_ (P_ * K_)        // 6912
#define TOTKP (B_ * M_)     // 13824
#define NS 16
#define R2C 0.04f
#define QDIM 864            // 32*K_

// ---------------- ws layout (bytes) ----------------
// kp4 : float4[TOTKP]   @ 0        (221184)
// cnt : int[TOTKP]      @ 221184   (55296)
// idx : int[TOTKP*16]   @ 276480   (884736)
// F   : float[B*N*128]  @ 1161216  (1048576)
// WrT : float[864*128]  @ 2209792  (442368)   total ~2.65 MB

// prep_k blockIdx ranges
#define PREP_WRT0    256      // 108 blocks
#define PREP_BALLQ0  364      // 3456 blocks
#define PREP_NBLK    3820

// ---------- kernel 1: fused prep = fpre + WrT transpose + ball query ----------
__global__ __launch_bounds__(256) void prep_k(
    const float* __restrict__ sf, const float* __restrict__ W1,
    const float* __restrict__ b1, const float* __restrict__ Wr,
    const float* __restrict__ seed_xyz, const float* __restrict__ boxes,
    const float* __restrict__ origins, const float* __restrict__ heading,
    float* __restrict__ F, float* __restrict__ WrT,
    float4* __restrict__ kp4, int* __restrict__ cntw, int* __restrict__ idxw)
{
    __shared__ __align__(16) float ssf[C_ * 8];
    int tid = threadIdx.x;
    int bid = blockIdx.x;

    if (bid < PREP_WRT0) {
        // ---- task A: F'[b,n,j] = b1[j] + sum_c sf[b,c,n]*W1[3+c,j] ----
        int b = bid >> 7;
        int n0 = (bid & 127) * 8;
        for (int e = tid; e < C_ * 8; e += 256) {
            int c = e >> 3, i = e & 7;
            ssf[e] = sf[(b * C_ + c) * N_ + n0 + i];
        }
        __syncthreads();
        int j = tid & 127;
        int h = tid >> 7;               // 4-seed half
        float acc[4];
        float bj = b1[j];
#pragma unroll
        for (int i = 0; i < 4; i++) acc[i] = bj;
#pragma unroll 8
        for (int c = 0; c < C_; ++c) {
            float w = W1[(3 + c) * 128 + j];
            float4 s = *(const float4*)&ssf[c * 8 + h * 4];
            acc[0] = fmaf(s.x, w, acc[0]);
            acc[1] = fmaf(s.y, w, acc[1]);
            acc[2] = fmaf(s.z, w, acc[2]);
            acc[3] = fmaf(s.w, w, acc[3]);
        }
#pragma unroll
        for (int i = 0; i < 4; i++)
            F[(b * N_ + n0 + h * 4 + i) * 128 + j] = acc[i];
    } else if (bid < PREP_BALLQ0) {
        // ---- task B: WrT[q][j] = Wr[j][q], float4 reads ----
        int e4 = (bid - PREP_WRT0) * 256 + tid;       // < 27648
        int j = e4 / 216, qq = e4 - j * 216;
        float4 v = ((const float4*)(Wr + j * QDIM))[qq];
        int q0 = qq * 4;
        WrT[(q0 + 0) * 128 + j] = v.x;
        WrT[(q0 + 1) * 128 + j] = v.y;
        WrT[(q0 + 2) * 128 + j] = v.z;
        WrT[(q0 + 3) * 128 + j] = v.w;
    } else {
        // ---- task C: keypoints + ball query (wave per keypoint) ----
        int wid = tid >> 6, lane = tid & 63;
        int kpg = (bid - PREP_BALLQ0) * 4 + wid;
        int b = kpg / M_;
        int m = kpg - b * M_;
        int p = m / K_, a = m - p * K_;

        const float* bx = boxes + (b * P_ + p) * 6;
        const float* og = origins + (b * P_ + p) * 3;
        float th = heading[b * P_ + p];
        float di = (float)(a / 9), dj = (float)((a / 3) % 3), dk = (float)(a % 3);
        float s0 = __fadd_rn(bx[0], bx[3]);
        float s1 = __fadd_rn(bx[1], bx[4]);
        float s2 = __fadd_rn(bx[2], bx[5]);
        float lx = __fsub_rn(__fmul_rn(__fdiv_rn(__fadd_rn(di, 0.5f), 3.0f), s0), bx[0]);
        float ly = __fsub_rn(__fmul_rn(__fdiv_rn(__fadd_rn(dj, 0.5f), 3.0f), s1), bx[1]);
        float lz = __fsub_rn(__fmul_rn(__fdiv_rn(__fadd_rn(dk, 0.5f), 3.0f), s2), bx[2]);
        float ct = cosf(th), st = sinf(th);
        float kx = __fadd_rn(__fadd_rn(__fmul_rn(lx, ct), __fmul_rn(ly, st)), og[0]);
        float ky = __fadd_rn(__fadd_rn(__fmul_rn(lx, -st), __fmul_rn(ly, ct)), og[1]);
        float kz = __fadd_rn(lz, og[2]);
        if (lane == 0) kp4[kpg] = make_float4(kx, ky, kz, 0.f);
        float kk = __fadd_rn(__fadd_rn(__fmul_rn(kx, kx), __fmul_rn(ky, ky)),
                             __fmul_rn(kz, kz));

        const float* sb = seed_xyz + b * (N_ * 3) + lane * 48;
        float f[48];
#pragma unroll
        for (int q = 0; q < 12; q++)
            ((float4*)f)[q] = ((const float4*)sb)[q];

        unsigned mask = 0;
#pragma unroll
        for (int i = 0; i < 16; i++) {
            float x = f[3 * i], y = f[3 * i + 1], z = f[3 * i + 2];
            float ss = __fadd_rn(__fadd_rn(__fmul_rn(x, x), __fmul_rn(y, y)),
                                 __fmul_rn(z, z));
            float dot = __fadd_rn(__fadd_rn(__fmul_rn(kx, x), __fmul_rn(ky, y)),
                                  __fmul_rn(kz, z));
            float d2 = __fsub_rn(__fadd_rn(kk, ss), __fmul_rn(2.0f, dot));
            mask |= (d2 < R2C ? 1u : 0u) << i;
        }

        int pc = __popc(mask);
        int incl = pc;
#pragma unroll
        for (int d = 1; d < 64; d <<= 1) {
            int v = __shfl_up(incl, d);
            if (lane >= d) incl += v;
        }
        int total = __shfl(incl, 63);
        int base = incl - pc;

        int* ip = idxw + kpg * NS;
        unsigned mm = mask;
        while (mm && base < NS) {
            int i = __ffs(mm) - 1;
            mm &= mm - 1;
            ip[base++] = lane * 16 + i;
        }
        if (lane == 0) cntw[kpg] = total < NS ? total : NS;
    }
}

// ---------- kernel 2: fused per-box MLP+maxpool+GEMM ----------
struct Ctx {
    const float* seed; const float* F;
    const float* sW2; const float* sW3;
    float* sH1; float* sH2;
    const int* ip;
    float4 kp;
    float w1x0, w1y0, w1z0, w1x1, w1y1, w1z1, b2j, b3t;
    int lane, t, jh, b, cnt, n0;
};

template <int GS>
static __device__ __forceinline__ void do_group(const Ctx& c, int s0, float& pool)
{
    float gx[GS], gy[GS], gz[GS];
    int nn[GS];
#pragma unroll
    for (int u = 0; u < GS; u++) {
        int s = s0 + u;
        int n = (s < c.cnt) ? c.ip[s] : c.n0;
        nn[u] = n;
        const float* sp = c.seed + (c.b * N_ + n) * 3;
        gx[u] = __fdiv_rn(__fsub_rn(sp[0], c.kp.x), 0.2f);
        gy[u] = __fdiv_rn(__fsub_rn(sp[1], c.kp.y), 0.2f);
        gz[u] = __fdiv_rn(__fsub_rn(sp[2], c.kp.z), 0.2f);
    }
#pragma unroll
    for (int u = 0; u < GS; u++) {
        const float* fp = c.F + (c.b * N_ + nn[u]) * 128;
        float v0 = fp[c.lane];
        float v1 = fp[c.lane + 64];
        v0 = fmaf(gx[u], c.w1x0, fmaf(gy[u], c.w1y0, fmaf(gz[u], c.w1z0, v0)));
        v1 = fmaf(gx[u], c.w1x1, fmaf(gy[u], c.w1y1, fmaf(gz[u], c.w1z1, v1)));
        c.sH1[u * 128 + c.lane] = fmaxf(v0, 0.f);
        c.sH1[u * 128 + c.lane + 64] = fmaxf(v1, 0.f);
    }
    float acc[GS];
#pragma unroll
    for (int u = 0; u < GS; u++) acc[u] = c.b2j;
#pragma unroll
    for (int cc = 0; cc < 128; cc += 4) {
        float w0 = c.sW2[(cc + 0) * 64 + c.lane];
        float w1 = c.sW2[(cc + 1) * 64 + c.lane];
        float w2 = c.sW2[(cc + 2) * 64 + c.lane];
        float w3 = c.sW2[(cc + 3) * 64 + c.lane];
#pragma unroll
        for (int u = 0; u < GS; u++) {
            float4 h = *(const float4*)&c.sH1[u * 128 + cc];
            acc[u] = fmaf(h.x, w0, fmaf(h.y, w1, fmaf(h.z, w2, fmaf(h.w, w3, acc[u]))));
        }
    }
#pragma unroll
    for (int u = 0; u < GS; u++) c.sH2[u * 64 + c.lane] = fmaxf(acc[u], 0.f);
    float a3[GS];
#pragma unroll
    for (int u = 0; u < GS; u++) a3[u] = (c.jh == 0) ? c.b3t : 0.f;
#pragma unroll
    for (int jj = 0; jj < 32; jj += 4) {
        int j0 = c.jh * 32 + jj;
        float w0 = c.sW3[(j0 + 0) * 32 + c.t];
        float w1 = c.sW3[(j0 + 1) * 32 + c.t];
        float w2 = c.sW3[(j0 + 2) * 32 + c.t];
        float w3 = c.sW3[(j0 + 3) * 32 + c.t];
#pragma unroll
        for (int u = 0; u < GS; u++) {
            float4 h = *(const float4*)&c.sH2[u * 64 + j0];
            a3[u] = fmaf(h.x, w0, fmaf(h.y, w1, fmaf(h.z, w2, fmaf(h.w, w3, a3[u]))));
        }
    }
#pragma unroll
    for (int u = 0; u < GS; u++) {
        float v = a3[u] + __shfl_xor(a3[u], 32);
        pool = fmaxf(pool, fmaxf(v, 0.f));
    }
}

// one block per (b,p) box: 27 keypoints -> ft[864] in LDS -> 864x128 GEMM -> out
__global__ __launch_bounds__(256, 2) void pf_k(
    const float* __restrict__ seed_xyz, const float* __restrict__ F,
    const float* __restrict__ W1, const float* __restrict__ b2g,
    const float* __restrict__ b3g, const float* __restrict__ W2g,
    const float* __restrict__ W3g, const float* __restrict__ WrT,
    const float* __restrict__ br, const float4* __restrict__ kp4,
    const int* __restrict__ cntw, const int* __restrict__ idxw,
    float* __restrict__ out)
{
    __shared__ __align__(16) float sW2[128 * 64];
    __shared__ __align__(16) float sW3[64 * 32];
    __shared__ __align__(16) float sH1[4 * 4 * 128];
    __shared__ __align__(16) float sH2[4 * 4 * 64];
    __shared__ __align__(16) float ft[QDIM];
    __shared__ __align__(16) float pj[128];
    int tid = threadIdx.x;
    for (int e = tid; e < 2048; e += 256)
        ((float4*)sW2)[e] = ((const float4*)W2g)[e];
    for (int e = tid; e < 512; e += 256)
        ((float4*)sW3)[e] = ((const float4*)W3g)[e];

    int wid = tid >> 6, lane = tid & 63;
    int bp = blockIdx.x;              // 0..511
    int b = bp >> 8, p = bp & 255;

    Ctx c;
    c.seed = seed_xyz; c.F = F;
    c.sW2 = sW2; c.sW3 = sW3;
    c.sH1 = sH1 + wid * 4 * 128;
    c.sH2 = sH2 + wid * 4 * 64;
    c.lane = lane; c.t = lane & 31; c.jh = lane >> 5;
    c.b = b;
    c.w1x0 = W1[lane];       c.w1x1 = W1[lane + 64];
    c.w1y0 = W1[128 + lane]; c.w1y1 = W1[128 + lane + 64];
    c.w1z0 = W1[256 + lane]; c.w1z1 = W1[256 + lane + 64];
    c.b2j = b2g[lane]; c.b3t = b3g[lane & 31];
    __syncthreads();                  // weights staged

    // ---- phase A: 27 keypoints, wave-strided; ft[j32*27 + k] = pooled ----
    for (int k = wid; k < K_; k += 4) {
        int kpg = bp * K_ + k;        // = b*M_ + p*K_ + k
        c.kp = kp4[kpg];
        c.cnt = cntw[kpg];
        c.ip = idxw + kpg * NS;
        c.n0 = (c.cnt > 0) ? c.ip[0] : 0;
        int scnt = c.cnt < 1 ? 1 : c.cnt;
        float pool = 0.f;
        for (int s0 = 0; s0 < scnt; s0 += 4) {
            int gs = scnt - s0; gs = gs > 4 ? 4 : gs;
            switch (gs) {
                case 1: do_group<1>(c, s0, pool); break;
                case 2: do_group<2>(c, s0, pool); break;
                case 3: do_group<3>(c, s0, pool); break;
                default: do_group<4>(c, s0, pool); break;
            }
        }
        if (lane < 32) ft[lane * K_ + k] = pool;
    }
    __syncthreads();

    // ---- phase B: out[b,j,p] = br[j] + sum_q ft[q]*WrT[q,j] ----
    int j = tid & 127;
    int h = tid >> 7;                 // K halves [0,432) / [432,864)
    float a = 0.f;
    const float* fq = ft + h * 432;
    const float* wq = WrT + (h * 432) * 128 + j;
#pragma unroll 4
    for (int q = 0; q < 432; ++q)
        a = fmaf(fq[q], wq[q * 128], a);
    if (h == 1) pj[j] = a;
    __syncthreads();
    if (h == 0)
        out[(b * 128 + j) * 256 + p] = a + pj[j] + br[j];
}

extern "C" void kernel_launch(void* const* d_in, const int* in_sizes, int n_in,
                              void* d_out, int out_size, void* d_ws, size_t ws_size,
                              hipStream_t stream)
{
    const float* seed_xyz  = (const float*)d_in[0];
    const float* seed_feat = (const float*)d_in[1];
    const float* boxes     = (const float*)d_in[2];
    const float* origins   = (const float*)d_in[3];
    const float* heading   = (const float*)d_in[4];
    const float* W1        = (const float*)d_in[5];
    const float* b1        = (const float*)d_in[6];
    const float* W2        = (const float*)d_in[7];
    const float* b2        = (const float*)d_in[8];
    const float* W3        = (const float*)d_in[9];
    const float* b3        = (const float*)d_in[10];
    const float* Wr        = (const float*)d_in[11];
    const float* br        = (const float*)d_in[12];
    float* out = (float*)d_out;

    char* ws = (char*)d_ws;
    float4* kp4  = (float4*)(ws);
    int*    cntw = (int*)(ws + 221184);
    int*    idxw = (int*)(ws + 276480);
    float*  F    = (float*)(ws + 1161216);
    float*  WrT  = (float*)(ws + 2209792);

    prep_k<<<dim3(PREP_NBLK), dim3(256), 0, stream>>>(
        seed_feat, W1, b1, Wr, seed_xyz, boxes, origins, heading,
        F, WrT, kp4, cntw, idxw);
    pf_k<<<dim3(512), dim3(256), 0, stream>>>(
        seed_xyz, F, W1, b2, b3, W2, W3, WrT, br, kp4, cntw, idxw, out);
}